// Round 6
// baseline (664.465 us; speedup 1.0000x reference)
//
#include <hip/hip_runtime.h>
#include <hip/hip_bf16.h>
#include <stdint.h>

// R6: OUTPUT IS FP32 (reference output dtype is float32; harness reads d_out
// as float*). The identical 1.73 error across two different attention kernels
// was the bf16-written/fp32-read pack artifact. GEMM epilogue now templated on
// output dtype; GEMM2 writes fp32. Inputs fp32 (confirmed R4). MFMA attention
// restored (R4 version, re-audited).
//   GEMM1: qkv[4096][6144] = x @ Wqkv^T       (fp32 in, bf16 out to ws)
//   ATTN : flash MFMA, block=(qt,h,b), online softmax (bf16 in/out ws)
//   GEMM2: out[4096][2048] = y @ Wproj^T      (bf16/fp32 in, FP32 out)

typedef __bf16 bf16x8 __attribute__((ext_vector_type(8)));
typedef float f32x4 __attribute__((ext_vector_type(4)));
typedef unsigned short u16x8 __attribute__((ext_vector_type(8)));

__device__ __forceinline__ unsigned short f2bf(float f) {
  unsigned int u = __builtin_bit_cast(unsigned int, f);
  u += 0x7fff + ((u >> 16) & 1);   // RNE; values are finite
  return (unsigned short)(u >> 16);
}

__device__ __forceinline__ u16x8 cvt8(const float* p) {
  f32x4 lo = *(const f32x4*)p;
  f32x4 hi = *(const f32x4*)(p + 4);
  u16x8 r;
#pragma unroll
  for (int j = 0; j < 4; j++) { r[j] = f2bf(lo[j]); r[4 + j] = f2bf(hi[j]); }
  return r;
}

// ---------------------------------------------------------------------------
// GEMM: C[M][N] = A[M][K] @ B[N][K]^T. A/B fp32 or bf16; C bf16 or fp32.
// 128x128 tile, BK=32, 256 threads (4 waves, each 64x64 as 4x4 of 16x16x32).
// ---------------------------------------------------------------------------
template <bool AF32, bool BF32, bool COF32>
__global__ __launch_bounds__(256) void gemm_bt(
    const void* __restrict__ Av, const void* __restrict__ Bv,
    void* __restrict__ Cv, int M, int N, int K) {
  __shared__ __align__(16) unsigned short Alds[128 * 32];
  __shared__ __align__(16) unsigned short Blds[128 * 32];

  const int tid  = threadIdx.x;
  const int lane = tid & 63;
  const int w    = tid >> 6;
  const int ln   = lane & 15;
  const int kq   = lane >> 4;
  const int m0 = blockIdx.y * 128;
  const int n0 = blockIdx.x * 128;
  const int m_base = (w >> 1) * 64;
  const int n_base = (w & 1) * 64;

  f32x4 acc[4][4];
#pragma unroll
  for (int i = 0; i < 4; i++)
#pragma unroll
    for (int j = 0; j < 4; j++) acc[i][j] = {0.f, 0.f, 0.f, 0.f};

  const int c0 = tid;          // [0,256)
  const int c1 = tid + 256;    // [256,512)
  const size_t ao0 = (size_t)(m0 + (c0 >> 2)) * K + (c0 & 3) * 8;
  const size_t ao1 = (size_t)(m0 + (c1 >> 2)) * K + (c1 & 3) * 8;
  const size_t bo0 = (size_t)(n0 + (c0 >> 2)) * K + (c0 & 3) * 8;
  const size_t bo1 = (size_t)(n0 + (c1 >> 2)) * K + (c1 & 3) * 8;

  const int nk = K >> 5;
  for (int kt = 0; kt < nk; kt++) {
    const int ko = kt * 32;
    u16x8 a0 = AF32 ? cvt8((const float*)Av + ao0 + ko)
                    : *(const u16x8*)((const unsigned short*)Av + ao0 + ko);
    u16x8 a1 = AF32 ? cvt8((const float*)Av + ao1 + ko)
                    : *(const u16x8*)((const unsigned short*)Av + ao1 + ko);
    u16x8 b0 = BF32 ? cvt8((const float*)Bv + bo0 + ko)
                    : *(const u16x8*)((const unsigned short*)Bv + bo0 + ko);
    u16x8 b1 = BF32 ? cvt8((const float*)Bv + bo1 + ko)
                    : *(const u16x8*)((const unsigned short*)Bv + bo1 + ko);
    *(u16x8*)&Alds[c0 * 8] = a0;
    *(u16x8*)&Alds[c1 * 8] = a1;
    *(u16x8*)&Blds[c0 * 8] = b0;
    *(u16x8*)&Blds[c1 * 8] = b1;
    __syncthreads();

    bf16x8 af[4], bfr[4];
#pragma unroll
    for (int i = 0; i < 4; i++)
      af[i] = *(const bf16x8*)&Alds[(m_base + i * 16 + ln) * 32 + kq * 8];
#pragma unroll
    for (int j = 0; j < 4; j++)
      bfr[j] = *(const bf16x8*)&Blds[(n_base + j * 16 + ln) * 32 + kq * 8];
#pragma unroll
    for (int i = 0; i < 4; i++)
#pragma unroll
      for (int j = 0; j < 4; j++)
        acc[i][j] = __builtin_amdgcn_mfma_f32_16x16x32_bf16(af[i], bfr[j], acc[i][j], 0, 0, 0);
    __syncthreads();
  }

  // Epilogue. C/D layout (m89): col = ln, row = kq*4 + r.
#pragma unroll
  for (int i = 0; i < 4; i++) {
    const int row_base = m0 + m_base + i * 16 + kq * 4;
#pragma unroll
    for (int j = 0; j < 4; j++) {
      const int col = n0 + n_base + j * 16 + ln;
#pragma unroll
      for (int r = 0; r < 4; r++) {
        const size_t idx = (size_t)(row_base + r) * N + col;
        if (COF32) ((float*)Cv)[idx] = acc[i][j][r];
        else       ((unsigned short*)Cv)[idx] = f2bf(acc[i][j][r]);
      }
    }
  }
}

// ---------------------------------------------------------------------------
// Flash attention (MFMA). qkv: [B*T][6144] bf16 (q|k|v, each 2048 = 16h*128).
// Block = (qt, h, b): 64 q-rows, 4 waves each own a 16-row strip.
// ---------------------------------------------------------------------------
#define TSEQ 2048
#define CDIM 2048
#define QKVLD 6144
#define DH 128
#define NEG_BIG (-1.0e30f)

__global__ __launch_bounds__(256) void attn(
    const unsigned short* __restrict__ qkv,
    unsigned short* __restrict__ y) {
  __shared__ __align__(16) unsigned short Klds[64 * 136];   // [key][d], pad 136
  __shared__ __align__(16) unsigned short Vt[128 * 72];     // [d][key], pad 72
  __shared__ __align__(16) unsigned short Plds[4 * 16 * 72];// per-wave [row][key]

  const int tid  = threadIdx.x;
  const int lane = tid & 63;
  const int w    = tid >> 6;
  const int ln   = lane & 15;
  const int kq   = lane >> 4;
  const int qt = blockIdx.x;
  const int h  = blockIdx.y;
  const int b  = blockIdx.z;
  const int q0 = qt * 64;

  const size_t baseQ = (size_t)b * TSEQ * QKVLD + (size_t)h * DH;
  const size_t baseK = baseQ + CDIM;
  const size_t baseV = baseQ + 2 * CDIM;

  // Q fragments (A-operand): row = q0 + w*16 + ln, d = kc*32 + kq*8 + j
  bf16x8 qf[4];
  {
    const unsigned short* qp = qkv + baseQ + (size_t)(q0 + w * 16 + ln) * QKVLD + kq * 8;
#pragma unroll
    for (int kc = 0; kc < 4; kc++) qf[kc] = *(const bf16x8*)(qp + kc * 32);
  }

  f32x4 o[8];
#pragma unroll
  for (int i = 0; i < 8; i++) o[i] = {0.f, 0.f, 0.f, 0.f};
  float mrow[4] = {NEG_BIG, NEG_BIG, NEG_BIG, NEG_BIG};
  float lrow[4] = {0.f, 0.f, 0.f, 0.f};
  const float scale = 0.08838834764831845f;  // 1/sqrt(128)

  for (int kt = 0; kt <= qt; kt++) {
    __syncthreads();  // previous iteration's LDS reads done

    // --- stage K tile [64][128] -> Klds[key][d]; 1024 chunks of 8 elems ---
#pragma unroll
    for (int it = 0; it < 4; it++) {
      const int chunk = tid + it * 256;
      const int key = chunk >> 4, dc = chunk & 15;
      u16x8 v = *(const u16x8*)(qkv + baseK + (size_t)(kt * 64 + key) * QKVLD + dc * 8);
      *(u16x8*)&Klds[key * 136 + dc * 8] = v;
    }
    // --- stage V tile transposed -> Vt[d][key] ---
    {
      const int key = tid & 63, dq = tid >> 6;
      const unsigned short* vp = qkv + baseV + (size_t)(kt * 64 + key) * QKVLD;
#pragma unroll
      for (int it = 0; it < 4; it++) {
        const int d0 = (it * 4 + dq) * 8;
        u16x8 v = *(const u16x8*)(vp + d0);
#pragma unroll
        for (int j = 0; j < 8; j++) Vt[(d0 + j) * 72 + key] = v[j];
      }
    }
    __syncthreads();

    // --- S = Q K^T (16x64 per wave) ---
    f32x4 s[4];
#pragma unroll
    for (int nt = 0; nt < 4; nt++) {
      s[nt] = {0.f, 0.f, 0.f, 0.f};
#pragma unroll
      for (int kc = 0; kc < 4; kc++) {
        bf16x8 kb = *(const bf16x8*)&Klds[(nt * 16 + ln) * 136 + kc * 32 + kq * 8];
        s[nt] = __builtin_amdgcn_mfma_f32_16x16x32_bf16(qf[kc], kb, s[nt], 0, 0, 0);
      }
    }

    // --- online softmax. lane holds rows rowb+r (r=0..3), col = nt*16+ln ---
    const int rowb = q0 + w * 16 + kq * 4;
    float mnew[4], alpha[4];
#pragma unroll
    for (int r = 0; r < 4; r++) {
      float mt = NEG_BIG;
#pragma unroll
      for (int nt = 0; nt < 4; nt++) {
        float sv = s[nt][r] * scale;
        if (kt == qt) {
          const int col = kt * 64 + nt * 16 + ln;
          if (col > rowb + r) sv = NEG_BIG;
        }
        s[nt][r] = sv;
        mt = fmaxf(mt, sv);
      }
#pragma unroll
      for (int off = 1; off < 16; off <<= 1)
        mt = fmaxf(mt, __shfl_xor(mt, off, 64));
      mnew[r]  = fmaxf(mrow[r], mt);
      alpha[r] = __expf(mrow[r] - mnew[r]);
      mrow[r]  = mnew[r];
    }

    // --- P = exp(S - m), row sums, P -> per-wave LDS (A-layout staging) ---
    unsigned short* pw = &Plds[w * 1152];
#pragma unroll
    for (int r = 0; r < 4; r++) {
      float rs = 0.f;
#pragma unroll
      for (int nt = 0; nt < 4; nt++) {
        const float p = __expf(s[nt][r] - mnew[r]);
        rs += p;
        pw[(kq * 4 + r) * 72 + nt * 16 + ln] = f2bf(p);
      }
#pragma unroll
      for (int off = 1; off < 16; off <<= 1) rs += __shfl_xor(rs, off, 64);
      lrow[r] = lrow[r] * alpha[r] + rs;
    }

    // --- rescale O ---
#pragma unroll
    for (int i = 0; i < 8; i++)
#pragma unroll
      for (int r = 0; r < 4; r++) o[i][r] = o[i][r] * alpha[r];

    // --- O += P V  (P per-wave region; same-wave DS ops are ordered) ---
    bf16x8 pa[2];
#pragma unroll
    for (int kc = 0; kc < 2; kc++)
      pa[kc] = *(const bf16x8*)&pw[ln * 72 + kc * 32 + kq * 8];
#pragma unroll
    for (int nt = 0; nt < 8; nt++)
#pragma unroll
      for (int kc = 0; kc < 2; kc++) {
        bf16x8 vb = *(const bf16x8*)&Vt[(nt * 16 + ln) * 72 + kc * 32 + kq * 8];
        o[nt] = __builtin_amdgcn_mfma_f32_16x16x32_bf16(pa[kc], vb, o[nt], 0, 0, 0);
      }
  }

  // --- epilogue: y[b*T + row][h*128 + d] = O / l ---
  const int rowb = q0 + w * 16 + kq * 4;
#pragma unroll
  for (int r = 0; r < 4; r++) {
    const float inv = 1.f / lrow[r];
    const size_t rb = (size_t)(b * TSEQ + rowb + r) * CDIM + (size_t)h * DH + ln;
#pragma unroll
    for (int nt = 0; nt < 8; nt++)
      y[rb + nt * 16] = f2bf(o[nt][r] * inv);
  }
}

extern "C" void kernel_launch(void* const* d_in, const int* in_sizes, int n_in,
                              void* d_out, int out_size, void* d_ws, size_t ws_size,
                              hipStream_t stream) {
  const void* x     = d_in[0];  // fp32 [4096][2048]
  const void* Wqkv  = d_in[1];  // fp32 [6144][2048]
  const void* Wproj = d_in[2];  // fp32 [2048][2048]
  void* out = d_out;                                  // FP32 [4096][2048]
  unsigned short* qkv = (unsigned short*)d_ws;        // bf16, 48MB
  unsigned short* y   = qkv + (size_t)4096 * 6144;    // bf16, 16MB

  gemm_bt<true, true, false><<<dim3(48, 32), 256, 0, stream>>>(x, Wqkv, qkv, 4096, 6144, 2048);
  attn<<<dim3(32, 16, 2), 256, 0, stream>>>(qkv, y);
  gemm_bt<false, true, true><<<dim3(16, 32), 256, 0, stream>>>(y, Wproj, out, 4096, 2048, 2048);
}

// Round 7
// 659.347 us; speedup vs baseline: 1.0078x; 1.0078x over previous
//
#include <hip/hip_runtime.h>
#include <hip/hip_bf16.h>
#include <stdint.h>

// R7: attn rework. (GEMMs unchanged from R6 — passed at absmax 7.8e-3.)
//  - Balanced pairing: block p handles q-tiles {p, 31-p}; one kt loop stages
//    each K/V tile ONCE and processes both q-tiles (A only while kt<=p).
//    512 uniform blocks (~33 MFMA-iters each) vs 1024 triangular.
//  - V transpose staged with 8x ds_write_b64 per thread (was 32x b16),
//    Vt pad 76; V global reads 4-lane 64B-contiguous.

typedef __bf16 bf16x8 __attribute__((ext_vector_type(8)));
typedef float f32x4 __attribute__((ext_vector_type(4)));
typedef unsigned short u16x8 __attribute__((ext_vector_type(8)));
typedef unsigned short u16x4 __attribute__((ext_vector_type(4)));

__device__ __forceinline__ unsigned short f2bf(float f) {
  unsigned int u = __builtin_bit_cast(unsigned int, f);
  u += 0x7fff + ((u >> 16) & 1);   // RNE; values are finite
  return (unsigned short)(u >> 16);
}

__device__ __forceinline__ u16x8 cvt8(const float* p) {
  f32x4 lo = *(const f32x4*)p;
  f32x4 hi = *(const f32x4*)(p + 4);
  u16x8 r;
#pragma unroll
  for (int j = 0; j < 4; j++) { r[j] = f2bf(lo[j]); r[4 + j] = f2bf(hi[j]); }
  return r;
}

// ---------------------------------------------------------------------------
// GEMM: C[M][N] = A[M][K] @ B[N][K]^T. A/B fp32 or bf16; C bf16 or fp32.
// 128x128 tile, BK=32, 256 threads (4 waves, each 64x64 as 4x4 of 16x16x32).
// ---------------------------------------------------------------------------
template <bool AF32, bool BF32, bool COF32>
__global__ __launch_bounds__(256) void gemm_bt(
    const void* __restrict__ Av, const void* __restrict__ Bv,
    void* __restrict__ Cv, int M, int N, int K) {
  __shared__ __align__(16) unsigned short Alds[128 * 32];
  __shared__ __align__(16) unsigned short Blds[128 * 32];

  const int tid  = threadIdx.x;
  const int lane = tid & 63;
  const int w    = tid >> 6;
  const int ln   = lane & 15;
  const int kq   = lane >> 4;
  const int m0 = blockIdx.y * 128;
  const int n0 = blockIdx.x * 128;
  const int m_base = (w >> 1) * 64;
  const int n_base = (w & 1) * 64;

  f32x4 acc[4][4];
#pragma unroll
  for (int i = 0; i < 4; i++)
#pragma unroll
    for (int j = 0; j < 4; j++) acc[i][j] = {0.f, 0.f, 0.f, 0.f};

  const int c0 = tid;          // [0,256)
  const int c1 = tid + 256;    // [256,512)
  const size_t ao0 = (size_t)(m0 + (c0 >> 2)) * K + (c0 & 3) * 8;
  const size_t ao1 = (size_t)(m0 + (c1 >> 2)) * K + (c1 & 3) * 8;
  const size_t bo0 = (size_t)(n0 + (c0 >> 2)) * K + (c0 & 3) * 8;
  const size_t bo1 = (size_t)(n0 + (c1 >> 2)) * K + (c1 & 3) * 8;

  const int nk = K >> 5;
  for (int kt = 0; kt < nk; kt++) {
    const int ko = kt * 32;
    u16x8 a0 = AF32 ? cvt8((const float*)Av + ao0 + ko)
                    : *(const u16x8*)((const unsigned short*)Av + ao0 + ko);
    u16x8 a1 = AF32 ? cvt8((const float*)Av + ao1 + ko)
                    : *(const u16x8*)((const unsigned short*)Av + ao1 + ko);
    u16x8 b0 = BF32 ? cvt8((const float*)Bv + bo0 + ko)
                    : *(const u16x8*)((const unsigned short*)Bv + bo0 + ko);
    u16x8 b1 = BF32 ? cvt8((const float*)Bv + bo1 + ko)
                    : *(const u16x8*)((const unsigned short*)Bv + bo1 + ko);
    *(u16x8*)&Alds[c0 * 8] = a0;
    *(u16x8*)&Alds[c1 * 8] = a1;
    *(u16x8*)&Blds[c0 * 8] = b0;
    *(u16x8*)&Blds[c1 * 8] = b1;
    __syncthreads();

    bf16x8 af[4], bfr[4];
#pragma unroll
    for (int i = 0; i < 4; i++)
      af[i] = *(const bf16x8*)&Alds[(m_base + i * 16 + ln) * 32 + kq * 8];
#pragma unroll
    for (int j = 0; j < 4; j++)
      bfr[j] = *(const bf16x8*)&Blds[(n_base + j * 16 + ln) * 32 + kq * 8];
#pragma unroll
    for (int i = 0; i < 4; i++)
#pragma unroll
      for (int j = 0; j < 4; j++)
        acc[i][j] = __builtin_amdgcn_mfma_f32_16x16x32_bf16(af[i], bfr[j], acc[i][j], 0, 0, 0);
    __syncthreads();
  }

  // Epilogue. C/D layout (m89): col = ln, row = kq*4 + r.
#pragma unroll
  for (int i = 0; i < 4; i++) {
    const int row_base = m0 + m_base + i * 16 + kq * 4;
#pragma unroll
    for (int j = 0; j < 4; j++) {
      const int col = n0 + n_base + j * 16 + ln;
#pragma unroll
      for (int r = 0; r < 4; r++) {
        const size_t idx = (size_t)(row_base + r) * N + col;
        if (COF32) ((float*)Cv)[idx] = acc[i][j][r];
        else       ((unsigned short*)Cv)[idx] = f2bf(acc[i][j][r]);
      }
    }
  }
}

// ---------------------------------------------------------------------------
// Flash attention (MFMA), balanced-pair blocks.
// qkv: [B*T][6144] bf16 (q|k|v, each 2048 = 16 heads * 128).
// Block (p,h,b) handles q-tiles qtA=p and qtB=31-p; K/V staged once per kt.
// ---------------------------------------------------------------------------
#define TSEQ 2048
#define CDIM 2048
#define QKVLD 6144
#define DH 128
#define NEG_BIG (-1.0e30f)
#define VT_LD 76

__device__ __forceinline__ void softmax_pv(
    f32x4 s[4], float mrow[4], float lrow[4], f32x4 o[8],
    const unsigned short* __restrict__ Vt, unsigned short* __restrict__ pw,
    int ln, int kq, int rowb, int kcol0, bool maskit) {
  const float scale = 0.08838834764831845f;  // 1/sqrt(128)
  float mnew[4], alpha[4];
#pragma unroll
  for (int r = 0; r < 4; r++) {
    float mt = NEG_BIG;
#pragma unroll
    for (int nt = 0; nt < 4; nt++) {
      float sv = s[nt][r] * scale;
      if (maskit && (kcol0 + nt * 16 + ln) > (rowb + r)) sv = NEG_BIG;
      s[nt][r] = sv;
      mt = fmaxf(mt, sv);
    }
#pragma unroll
    for (int off = 1; off < 16; off <<= 1)
      mt = fmaxf(mt, __shfl_xor(mt, off, 64));
    mnew[r]  = fmaxf(mrow[r], mt);
    alpha[r] = __expf(mrow[r] - mnew[r]);
    mrow[r]  = mnew[r];
  }
#pragma unroll
  for (int r = 0; r < 4; r++) {
    float rs = 0.f;
#pragma unroll
    for (int nt = 0; nt < 4; nt++) {
      const float p = __expf(s[nt][r] - mnew[r]);
      rs += p;
      pw[(kq * 4 + r) * 72 + nt * 16 + ln] = f2bf(p);
    }
#pragma unroll
    for (int off = 1; off < 16; off <<= 1) rs += __shfl_xor(rs, off, 64);
    lrow[r] = lrow[r] * alpha[r] + rs;
  }
#pragma unroll
  for (int i = 0; i < 8; i++)
#pragma unroll
    for (int r = 0; r < 4; r++) o[i][r] = o[i][r] * alpha[r];

  bf16x8 pa[2];
#pragma unroll
  for (int kc = 0; kc < 2; kc++)
    pa[kc] = *(const bf16x8*)&pw[ln * 72 + kc * 32 + kq * 8];
#pragma unroll
  for (int nt = 0; nt < 8; nt++)
#pragma unroll
    for (int kc = 0; kc < 2; kc++) {
      bf16x8 vb = *(const bf16x8*)&Vt[(nt * 16 + ln) * VT_LD + kc * 32 + kq * 8];
      o[nt] = __builtin_amdgcn_mfma_f32_16x16x32_bf16(pa[kc], vb, o[nt], 0, 0, 0);
    }
}

__global__ __launch_bounds__(256) void attn(
    const unsigned short* __restrict__ qkv,
    unsigned short* __restrict__ y) {
  __shared__ __align__(16) unsigned short Klds[64 * 136];     // [key][d]
  __shared__ __align__(16) unsigned short Vt[128 * VT_LD];    // [d][key]
  __shared__ __align__(16) unsigned short Plds[4 * 16 * 72];  // per-wave P

  const int tid  = threadIdx.x;
  const int lane = tid & 63;
  const int w    = tid >> 6;
  const int ln   = lane & 15;
  const int kq   = lane >> 4;
  const int p  = blockIdx.x;      // pair index [0,16)
  const int h  = blockIdx.y;
  const int b  = blockIdx.z;
  const int qtA = p, qtB = 31 - p;

  const size_t baseQ = (size_t)b * TSEQ * QKVLD + (size_t)h * DH;
  const size_t baseK = baseQ + CDIM;
  const size_t baseV = baseQ + 2 * CDIM;

  // Q fragments (A-operand): row = qt*64 + w*16 + ln, d = kc*32 + kq*8 + j
  bf16x8 qfA[4], qfB[4];
  {
    const unsigned short* qa = qkv + baseQ + (size_t)(qtA * 64 + w * 16 + ln) * QKVLD + kq * 8;
    const unsigned short* qb = qkv + baseQ + (size_t)(qtB * 64 + w * 16 + ln) * QKVLD + kq * 8;
#pragma unroll
    for (int kc = 0; kc < 4; kc++) {
      qfA[kc] = *(const bf16x8*)(qa + kc * 32);
      qfB[kc] = *(const bf16x8*)(qb + kc * 32);
    }
  }

  f32x4 oA[8], oB[8];
#pragma unroll
  for (int i = 0; i < 8; i++) { oA[i] = {0.f,0.f,0.f,0.f}; oB[i] = {0.f,0.f,0.f,0.f}; }
  float mA[4] = {NEG_BIG,NEG_BIG,NEG_BIG,NEG_BIG}, lA[4] = {0.f,0.f,0.f,0.f};
  float mB[4] = {NEG_BIG,NEG_BIG,NEG_BIG,NEG_BIG}, lB[4] = {0.f,0.f,0.f,0.f};
  const int rowbA = qtA * 64 + w * 16 + kq * 4;
  const int rowbB = qtB * 64 + w * 16 + kq * 4;
  unsigned short* pw = &Plds[w * 1152];

  for (int kt = 0; kt <= qtB; kt++) {
    __syncthreads();  // previous iteration's LDS reads done

    // --- stage K tile [64][128] -> Klds[key][d]; 1024 chunks of 8 elems ---
#pragma unroll
    for (int it = 0; it < 4; it++) {
      const int chunk = tid + it * 256;
      const int key = chunk >> 4, dc = chunk & 15;
      u16x8 v = *(const u16x8*)(qkv + baseK + (size_t)(kt * 64 + key) * QKVLD + dc * 8);
      *(u16x8*)&Klds[key * 136 + dc * 8] = v;
    }
    // --- stage V transposed: thread = 4 consecutive keys x 8 d; b64 writes
    {
      const int k4 = (tid & 15) * 4;
      const int d0 = (tid >> 4) * 8;
      const unsigned short* vp = qkv + baseV + (size_t)(kt * 64 + k4) * QKVLD + d0;
      u16x8 v0 = *(const u16x8*)(vp);
      u16x8 v1 = *(const u16x8*)(vp + QKVLD);
      u16x8 v2 = *(const u16x8*)(vp + 2 * QKVLD);
      u16x8 v3 = *(const u16x8*)(vp + 3 * QKVLD);
#pragma unroll
      for (int j = 0; j < 8; j++) {
        u16x4 t = {v0[j], v1[j], v2[j], v3[j]};
        *(u16x4*)&Vt[(d0 + j) * VT_LD + k4] = t;
      }
    }
    __syncthreads();

    // --- tile A (only while kt <= qtA) ---
    if (kt <= qtA) {
      f32x4 s[4];
#pragma unroll
      for (int nt = 0; nt < 4; nt++) {
        s[nt] = {0.f, 0.f, 0.f, 0.f};
#pragma unroll
        for (int kc = 0; kc < 4; kc++) {
          bf16x8 kb = *(const bf16x8*)&Klds[(nt * 16 + ln) * 136 + kc * 32 + kq * 8];
          s[nt] = __builtin_amdgcn_mfma_f32_16x16x32_bf16(qfA[kc], kb, s[nt], 0, 0, 0);
        }
      }
      softmax_pv(s, mA, lA, oA, Vt, pw, ln, kq, rowbA, kt * 64, kt == qtA);
    }
    // --- tile B (always) ---
    {
      f32x4 s[4];
#pragma unroll
      for (int nt = 0; nt < 4; nt++) {
        s[nt] = {0.f, 0.f, 0.f, 0.f};
#pragma unroll
        for (int kc = 0; kc < 4; kc++) {
          bf16x8 kb = *(const bf16x8*)&Klds[(nt * 16 + ln) * 136 + kc * 32 + kq * 8];
          s[nt] = __builtin_amdgcn_mfma_f32_16x16x32_bf16(qfB[kc], kb, s[nt], 0, 0, 0);
        }
      }
      softmax_pv(s, mB, lB, oB, Vt, pw, ln, kq, rowbB, kt * 64, kt == qtB);
    }
  }

  // --- epilogue: y[b*T + row][h*128 + d] = O / l ---
#pragma unroll
  for (int r = 0; r < 4; r++) {
    const float invA = 1.f / lA[r];
    const float invB = 1.f / lB[r];
    const size_t rbA = (size_t)(b * TSEQ + rowbA + r) * CDIM + (size_t)h * DH + ln;
    const size_t rbB = (size_t)(b * TSEQ + rowbB + r) * CDIM + (size_t)h * DH + ln;
#pragma unroll
    for (int nt = 0; nt < 8; nt++) {
      y[rbA + nt * 16] = f2bf(oA[nt][r] * invA);
      y[rbB + nt * 16] = f2bf(oB[nt][r] * invB);
    }
  }
}

extern "C" void kernel_launch(void* const* d_in, const int* in_sizes, int n_in,
                              void* d_out, int out_size, void* d_ws, size_t ws_size,
                              hipStream_t stream) {
  const void* x     = d_in[0];  // fp32 [4096][2048]
  const void* Wqkv  = d_in[1];  // fp32 [6144][2048]
  const void* Wproj = d_in[2];  // fp32 [2048][2048]
  void* out = d_out;                                  // fp32 [4096][2048]
  unsigned short* qkv = (unsigned short*)d_ws;        // bf16, 48MB
  unsigned short* y   = qkv + (size_t)4096 * 6144;    // bf16, 16MB

  gemm_bt<true, true, false><<<dim3(48, 32), 256, 0, stream>>>(x, Wqkv, qkv, 4096, 6144, 2048);
  attn<<<dim3(16, 16, 2), 256, 0, stream>>>(qkv, y);
  gemm_bt<false, true, true><<<dim3(16, 32), 256, 0, stream>>>(y, Wproj, out, 4096, 2048, 2048);
}

// Round 8
// 518.492 us; speedup vs baseline: 1.2815x; 1.2717x over previous
//
#include <hip/hip_runtime.h>
#include <hip/hip_bf16.h>
#include <stdint.h>

// R8: attn rewritten as TRANSPOSED flash (S^T = K Q^T, O^T = V^T P^T) with
// per-lane scalar softmax state + register-prefetched K/V staging.
//  - A/B frag layouts are lane-symmetric, so swapping MFMA operand order
//    reuses R7's verified LDS read patterns; C/D col=ln becomes the q index.
//  - shuffles 32->4 /iter, expf 40->17, P->LDS 4x ds_write_b64, y 8x b64.
//  - K/V for iter kt+1 loaded into regs during compute of iter kt.
// GEMMs unchanged (R6-verified).

typedef __bf16 bf16x8 __attribute__((ext_vector_type(8)));
typedef float f32x4 __attribute__((ext_vector_type(4)));
typedef unsigned short u16x8 __attribute__((ext_vector_type(8)));
typedef unsigned short u16x4 __attribute__((ext_vector_type(4)));

__device__ __forceinline__ unsigned short f2bf(float f) {
  unsigned int u = __builtin_bit_cast(unsigned int, f);
  u += 0x7fff + ((u >> 16) & 1);   // RNE; values are finite
  return (unsigned short)(u >> 16);
}
__device__ __forceinline__ float bf2f(unsigned short u) {
  return __builtin_bit_cast(float, (unsigned int)u << 16);
}

__device__ __forceinline__ u16x8 cvt8(const float* p) {
  f32x4 lo = *(const f32x4*)p;
  f32x4 hi = *(const f32x4*)(p + 4);
  u16x8 r;
#pragma unroll
  for (int j = 0; j < 4; j++) { r[j] = f2bf(lo[j]); r[4 + j] = f2bf(hi[j]); }
  return r;
}

// ---------------------------------------------------------------------------
// GEMM: C[M][N] = A[M][K] @ B[N][K]^T. A/B fp32 or bf16; C bf16 or fp32.
// 128x128 tile, BK=32, 256 threads (4 waves, each 64x64 as 4x4 of 16x16x32).
// ---------------------------------------------------------------------------
template <bool AF32, bool BF32, bool COF32>
__global__ __launch_bounds__(256) void gemm_bt(
    const void* __restrict__ Av, const void* __restrict__ Bv,
    void* __restrict__ Cv, int M, int N, int K) {
  __shared__ __align__(16) unsigned short Alds[128 * 32];
  __shared__ __align__(16) unsigned short Blds[128 * 32];

  const int tid  = threadIdx.x;
  const int lane = tid & 63;
  const int w    = tid >> 6;
  const int ln   = lane & 15;
  const int kq   = lane >> 4;
  const int m0 = blockIdx.y * 128;
  const int n0 = blockIdx.x * 128;
  const int m_base = (w >> 1) * 64;
  const int n_base = (w & 1) * 64;

  f32x4 acc[4][4];
#pragma unroll
  for (int i = 0; i < 4; i++)
#pragma unroll
    for (int j = 0; j < 4; j++) acc[i][j] = {0.f, 0.f, 0.f, 0.f};

  const int c0 = tid;          // [0,256)
  const int c1 = tid + 256;    // [256,512)
  const size_t ao0 = (size_t)(m0 + (c0 >> 2)) * K + (c0 & 3) * 8;
  const size_t ao1 = (size_t)(m0 + (c1 >> 2)) * K + (c1 & 3) * 8;
  const size_t bo0 = (size_t)(n0 + (c0 >> 2)) * K + (c0 & 3) * 8;
  const size_t bo1 = (size_t)(n0 + (c1 >> 2)) * K + (c1 & 3) * 8;

  const int nk = K >> 5;
  for (int kt = 0; kt < nk; kt++) {
    const int ko = kt * 32;
    u16x8 a0 = AF32 ? cvt8((const float*)Av + ao0 + ko)
                    : *(const u16x8*)((const unsigned short*)Av + ao0 + ko);
    u16x8 a1 = AF32 ? cvt8((const float*)Av + ao1 + ko)
                    : *(const u16x8*)((const unsigned short*)Av + ao1 + ko);
    u16x8 b0 = BF32 ? cvt8((const float*)Bv + bo0 + ko)
                    : *(const u16x8*)((const unsigned short*)Bv + bo0 + ko);
    u16x8 b1 = BF32 ? cvt8((const float*)Bv + bo1 + ko)
                    : *(const u16x8*)((const unsigned short*)Bv + bo1 + ko);
    *(u16x8*)&Alds[c0 * 8] = a0;
    *(u16x8*)&Alds[c1 * 8] = a1;
    *(u16x8*)&Blds[c0 * 8] = b0;
    *(u16x8*)&Blds[c1 * 8] = b1;
    __syncthreads();

    bf16x8 af[4], bfr[4];
#pragma unroll
    for (int i = 0; i < 4; i++)
      af[i] = *(const bf16x8*)&Alds[(m_base + i * 16 + ln) * 32 + kq * 8];
#pragma unroll
    for (int j = 0; j < 4; j++)
      bfr[j] = *(const bf16x8*)&Blds[(n_base + j * 16 + ln) * 32 + kq * 8];
#pragma unroll
    for (int i = 0; i < 4; i++)
#pragma unroll
      for (int j = 0; j < 4; j++)
        acc[i][j] = __builtin_amdgcn_mfma_f32_16x16x32_bf16(af[i], bfr[j], acc[i][j], 0, 0, 0);
    __syncthreads();
  }

  // Epilogue. C/D layout (m89): col = ln, row = kq*4 + r.
#pragma unroll
  for (int i = 0; i < 4; i++) {
    const int row_base = m0 + m_base + i * 16 + kq * 4;
#pragma unroll
    for (int j = 0; j < 4; j++) {
      const int col = n0 + n_base + j * 16 + ln;
#pragma unroll
      for (int r = 0; r < 4; r++) {
        const size_t idx = (size_t)(row_base + r) * N + col;
        if (COF32) ((float*)Cv)[idx] = acc[i][j][r];
        else       ((unsigned short*)Cv)[idx] = f2bf(acc[i][j][r]);
      }
    }
  }
}

// ---------------------------------------------------------------------------
// Transposed flash attention. qkv: [B*T][6144] bf16 (q|k|v, 2048 each).
// Block (qt,h,b): 64 q rows; wave w owns q rows q0+w*16+ln (one per lane).
// S^T = K.Q^T  : D[m=key=kq*4+r (per nt)][n=q=ln]
// O^T = V^T.P^T: D[m=d=nt*16+kq*4+r][n=q=ln]
// ---------------------------------------------------------------------------
#define TSEQ 2048
#define CDIM 2048
#define QKVLD 6144
#define DH 128
#define NEG_BIG (-1.0e30f)
#define K_LD 136
#define VT_LD 76
#define P_LD 72

__global__ __launch_bounds__(256) void attn(
    const unsigned short* __restrict__ qkv,
    unsigned short* __restrict__ y) {
  __shared__ __align__(16) unsigned short Klds[64 * K_LD];    // [key][d]
  __shared__ __align__(16) unsigned short Vt[DH * VT_LD];     // [d][key]
  __shared__ __align__(16) unsigned short Plds[4 * 16 * P_LD];// per-wave [q][key]

  const int tid  = threadIdx.x;
  const int lane = tid & 63;
  const int w    = tid >> 6;
  const int ln   = lane & 15;
  const int kq   = lane >> 4;
  const int qt = blockIdx.x;
  const int h  = blockIdx.y;
  const int b  = blockIdx.z;
  const int q0 = qt * 64;
  const int qrow = q0 + w * 16 + ln;      // this lane's q row (global in seq)

  const size_t baseQ = (size_t)b * TSEQ * QKVLD + (size_t)h * DH;
  const size_t baseK = baseQ + CDIM;
  const size_t baseV = baseQ + 2 * CDIM;

  // Q fragments (B-operand), pre-scaled by 1/sqrt(128).
  bf16x8 qf[4];
  {
    const float scale = 0.08838834764831845f;
    const unsigned short* qp = qkv + baseQ + (size_t)qrow * QKVLD + kq * 8;
#pragma unroll
    for (int kc = 0; kc < 4; kc++) {
      u16x8 raw = *(const u16x8*)(qp + kc * 32);
      u16x8 t;
#pragma unroll
      for (int j = 0; j < 8; j++) t[j] = f2bf(bf2f(raw[j]) * scale);
      qf[kc] = __builtin_bit_cast(bf16x8, t);
    }
  }

  // staging addresses
  const int kRow = tid >> 4;                 // K: key row base (16 rows/iter grp)
  const int kCol = (tid & 15) * 8;           // K: d offset
  const int vK4  = (tid & 15) * 4;           // V: 4 consecutive keys
  const int vD0  = (tid >> 4) * 8;           // V: 8 d elems
  const unsigned short* Kg = qkv + baseK + (size_t)kRow * QKVLD + kCol;
  const unsigned short* Vg = qkv + baseV + (size_t)vK4 * QKVLD + vD0;

  u16x8 kreg[4], vreg[4];
#pragma unroll
  for (int it = 0; it < 4; it++)
    kreg[it] = *(const u16x8*)(Kg + (size_t)(it * 16) * QKVLD);
#pragma unroll
  for (int r = 0; r < 4; r++)
    vreg[r] = *(const u16x8*)(Vg + (size_t)r * QKVLD);

  f32x4 o[8];
#pragma unroll
  for (int i = 0; i < 8; i++) o[i] = {0.f, 0.f, 0.f, 0.f};
  float m = NEG_BIG, l = 0.f;
  unsigned short* pw = &Plds[w * 16 * P_LD];

  for (int kt = 0; kt <= qt; kt++) {
    __syncthreads();  // previous iteration's LDS reads done

    // commit prefetched tile to LDS
#pragma unroll
    for (int it = 0; it < 4; it++)
      *(u16x8*)&Klds[(kRow + it * 16) * K_LD + kCol] = kreg[it];
#pragma unroll
    for (int j = 0; j < 8; j++) {
      u16x4 t = {vreg[0][j], vreg[1][j], vreg[2][j], vreg[3][j]};
      *(u16x4*)&Vt[(vD0 + j) * VT_LD + vK4] = t;
    }
    __syncthreads();

    // prefetch next tile (no wait; overlaps compute)
    if (kt < qt) {
      const size_t off = (size_t)(kt + 1) * 64 * QKVLD;
#pragma unroll
      for (int it = 0; it < 4; it++)
        kreg[it] = *(const u16x8*)(Kg + off + (size_t)(it * 16) * QKVLD);
#pragma unroll
      for (int r = 0; r < 4; r++)
        vreg[r] = *(const u16x8*)(Vg + off + (size_t)r * QKVLD);
    }

    // --- S^T = K Q^T : s[nt][r] = S[key = kt*64+nt*16+kq*4+r][q = qrow] ---
    f32x4 s[4];
#pragma unroll
    for (int nt = 0; nt < 4; nt++) {
      s[nt] = {0.f, 0.f, 0.f, 0.f};
#pragma unroll
      for (int kc = 0; kc < 4; kc++) {
        bf16x8 kb = *(const bf16x8*)&Klds[(nt * 16 + ln) * K_LD + kc * 32 + kq * 8];
        s[nt] = __builtin_amdgcn_mfma_f32_16x16x32_bf16(kb, qf[kc], s[nt], 0, 0, 0);
      }
    }

    // --- causal mask (only on the diagonal tile) ---
    if (kt == qt) {
      const int kbase = kt * 64 + kq * 4;
#pragma unroll
      for (int nt = 0; nt < 4; nt++)
#pragma unroll
        for (int r = 0; r < 4; r++)
          if (kbase + nt * 16 + r > qrow) s[nt][r] = NEG_BIG;
    }

    // --- per-lane online softmax (lane owns one q row) ---
    float mt;
    {
      f32x4 t01 = {fmaxf(s[0][0], s[0][1]), fmaxf(s[0][2], s[0][3]),
                   fmaxf(s[1][0], s[1][1]), fmaxf(s[1][2], s[1][3])};
      f32x4 t23 = {fmaxf(s[2][0], s[2][1]), fmaxf(s[2][2], s[2][3]),
                   fmaxf(s[3][0], s[3][1]), fmaxf(s[3][2], s[3][3])};
      f32x4 t = {fmaxf(t01[0], t01[1]), fmaxf(t01[2], t01[3]),
                 fmaxf(t23[0], t23[1]), fmaxf(t23[2], t23[3])};
      mt = fmaxf(fmaxf(t[0], t[1]), fmaxf(t[2], t[3]));
    }
    mt = fmaxf(mt, __shfl_xor(mt, 16, 64));
    mt = fmaxf(mt, __shfl_xor(mt, 32, 64));
    const float mn = fmaxf(m, mt);
    const float alpha = __expf(m - mn);
    m = mn;

    float ps = 0.f;
#pragma unroll
    for (int nt = 0; nt < 4; nt++) {
      u16x4 pbits;
#pragma unroll
      for (int r = 0; r < 4; r++) {
        const float p = __expf(s[nt][r] - mn);
        ps += p;
        pbits[r] = f2bf(p);
      }
      *(u16x4*)&pw[ln * P_LD + nt * 16 + kq * 4] = pbits;  // P[q=ln][key]
    }
    ps += __shfl_xor(ps, 16, 64);
    ps += __shfl_xor(ps, 32, 64);
    l = l * alpha + ps;

#pragma unroll
    for (int i = 0; i < 8; i++)
#pragma unroll
      for (int r = 0; r < 4; r++) o[i][r] *= alpha;

    // --- O^T += V^T P^T (P read back as B-frag; same-wave DS in order) ---
    bf16x8 pa[2];
#pragma unroll
    for (int kc = 0; kc < 2; kc++)
      pa[kc] = *(const bf16x8*)&pw[ln * P_LD + kc * 32 + kq * 8];
#pragma unroll
    for (int nt = 0; nt < 8; nt++)
#pragma unroll
      for (int kc = 0; kc < 2; kc++) {
        bf16x8 vb = *(const bf16x8*)&Vt[(nt * 16 + ln) * VT_LD + kc * 32 + kq * 8];
        o[nt] = __builtin_amdgcn_mfma_f32_16x16x32_bf16(vb, pa[kc], o[nt], 0, 0, 0);
      }
  }

  // --- epilogue: o[nt][r] = O[q=qrow][d = nt*16 + kq*4 + r] ---
  const float inv = 1.f / l;
  unsigned short* yp = y + (size_t)(b * TSEQ + qrow) * CDIM + (size_t)h * DH + kq * 4;
#pragma unroll
  for (int nt = 0; nt < 8; nt++) {
    u16x4 ov;
#pragma unroll
    for (int r = 0; r < 4; r++) ov[r] = f2bf(o[nt][r] * inv);
    *(u16x4*)(yp + nt * 16) = ov;
  }
}

extern "C" void kernel_launch(void* const* d_in, const int* in_sizes, int n_in,
                              void* d_out, int out_size, void* d_ws, size_t ws_size,
                              hipStream_t stream) {
  const void* x     = d_in[0];  // fp32 [4096][2048]
  const void* Wqkv  = d_in[1];  // fp32 [6144][2048]
  const void* Wproj = d_in[2];  // fp32 [2048][2048]
  void* out = d_out;                                  // fp32 [4096][2048]
  unsigned short* qkv = (unsigned short*)d_ws;        // bf16, 48MB
  unsigned short* y   = qkv + (size_t)4096 * 6144;    // bf16, 16MB

  gemm_bt<true, true, false><<<dim3(48, 32), 256, 0, stream>>>(x, Wqkv, qkv, 4096, 6144, 2048);
  attn<<<dim3(32, 16, 2), 256, 0, stream>>>(qkv, y);
  gemm_bt<false, true, true><<<dim3(16, 32), 256, 0, stream>>>(y, Wproj, out, 4096, 2048, 2048);
}